// Round 2
// baseline (10534.971 us; speedup 1.0000x reference)
//
#include <hip/hip_runtime.h>

// ---------------------------------------------------------------------------
// TorchAttractorLanguageModel: embedding->LN->L2 signals, 960-step nonlinear
// scan (rows independent -> no cross-block sync), then -cdist/temp logits.
// Round 1: resubmit of round-0 all-f32 kernel (round-1 bench was an infra
// failure: GPUAcquisitionTimeout, no data).
// ---------------------------------------------------------------------------

static constexpr int   kB     = 256;
static constexpr int   kT     = 32;
static constexpr int   kV     = 50257;
static constexpr int   kD     = 512;
static constexpr int   kSteps = 30;
static constexpr float kDT    = 0.04f;
static constexpr float kCubic = 0.008f;
static constexpr float kEpsLN = 1e-5f;

static constexpr int RR          = 3;                    // state rows per scan block
static constexpr int SCAN_BLOCKS = (kB + RR - 1) / RR;   // 86
static constexpr int VT          = 32;                   // v-columns per logits block

// ---------------------------------------------------------------------------
// K1: all_sigs[v] = L2normalize(LayerNorm(emb[v]))  (no affine, biased var)
// One block per vocab row, 128 threads * float4.
__global__ __launch_bounds__(128)
void k_signals(const float* __restrict__ emb, float* __restrict__ sigs) {
  const int row = blockIdx.x;
  const int tid = threadIdx.x;
  const float4 x = reinterpret_cast<const float4*>(emb + (size_t)row * kD)[tid];
  float s = x.x + x.y + x.z + x.w;
  float q = x.x * x.x + x.y * x.y + x.z * x.z + x.w * x.w;
#pragma unroll
  for (int o = 32; o > 0; o >>= 1) {
    s += __shfl_xor(s, o);
    q += __shfl_xor(q, o);
  }
  __shared__ float ls[2], lq[2];
  const int wid = tid >> 6;
  if ((tid & 63) == 0) { ls[wid] = s; lq[wid] = q; }
  __syncthreads();
  s = ls[0] + ls[1];
  q = lq[0] + lq[1];
  const float mu   = s * (1.0f / kD);
  const float var  = fmaxf(q * (1.0f / kD) - mu * mu, 0.0f);
  const float rstd = rsqrtf(var + kEpsLN);
  // ||(x-mu)*rstd|| = rstd * sqrt(D*var)   (closed form; avoids 2nd reduce)
  const float n     = rstd * sqrtf((float)kD * var);
  const float scale = rstd / fmaxf(n, 1e-12f);
  float4 y;
  y.x = (x.x - mu) * scale;
  y.y = (x.y - mu) * scale;
  y.z = (x.z - mu) * scale;
  y.w = (x.w - mu) * scale;
  reinterpret_cast<float4*>(sigs + (size_t)row * kD)[tid] = y;
}

// ---------------------------------------------------------------------------
// K2: stage diffusion into W[c][j][4] = Dif[j][4c..4c+3] so that the scan's
// per-thread (thread==output j) float4 stream over k is fully coalesced.
__global__ __launch_bounds__(256)
void k_wprep(const float* __restrict__ dif, float4* __restrict__ w4) {
  const int idx = blockIdx.x * 256 + threadIdx.x;   // 128*512 = 65536 total
  const int c = idx >> 9;
  const int j = idx & 511;
  w4[idx] = reinterpret_cast<const float4*>(dif + (size_t)j * kD)[c];
}

// ---------------------------------------------------------------------------
// K3: the scan. One block owns RR independent state rows for all T*30 steps.
// s broadcast from LDS; diffusion streamed from L2 via the coalesced W layout.
__global__ __launch_bounds__(512)
void k_scan(const int* __restrict__ ids, const float* __restrict__ sigs,
            const float4* __restrict__ w4, float* __restrict__ state,
            float* __restrict__ ssq) {
  const int tid  = threadIdx.x;        // == output element j
  const int b0   = blockIdx.x * RR;
  const int wid  = tid >> 6;
  const int lane = tid & 63;

  __shared__ float4 s4[RR][kD / 4];
  __shared__ float  red[RR][8];
  float* s_lin = reinterpret_cast<float*>(s4);

  float s_reg[RR], sig[RR];
#pragma unroll
  for (int r = 0; r < RR; ++r) { s_reg[r] = 0.0f; s_lin[r * kD + tid] = 0.0f; }
  __syncthreads();

  for (int t = 0; t < kT; ++t) {
#pragma unroll
    for (int r = 0; r < RR; ++r) {
      int bb = b0 + r; if (bb >= kB) bb = 0;          // padded rows: harmless
      const int id = ids[bb * kT + t];
      sig[r] = sigs[(size_t)id * kD + tid];
    }
    for (int step = 0; step < kSteps; ++step) {
      // --- mean over D (wave shuffle + LDS combine) ---
      float part[RR];
#pragma unroll
      for (int r = 0; r < RR; ++r) part[r] = s_reg[r];
#pragma unroll
      for (int o = 32; o > 0; o >>= 1) {
#pragma unroll
        for (int r = 0; r < RR; ++r) part[r] += __shfl_xor(part[r], o);
      }
      if (lane == 0) {
#pragma unroll
        for (int r = 0; r < RR; ++r) red[r][wid] = part[r];
      }
      __syncthreads();                  // red + s4 from last step visible
      float mean[RR];
#pragma unroll
      for (int r = 0; r < RR; ++r) {
        float m = 0.0f;
#pragma unroll
        for (int w = 0; w < 8; ++w) m += red[r][w];
        mean[r] = m * (1.0f / kD);
      }
      // --- y[j] = sum_k s[k]*Dif[j,k] : stream W, broadcast s from LDS ---
      float acc[RR];
#pragma unroll
      for (int r = 0; r < RR; ++r) acc[r] = 0.0f;
      const float4* __restrict__ wp = w4 + tid;
#pragma unroll 4
      for (int c = 0; c < kD / 4; ++c) {
        const float4 w = wp[(size_t)c << 9];
#pragma unroll
        for (int r = 0; r < RR; ++r) {
          const float4 sv = s4[r][c];
          acc[r] = fmaf(sv.x, w.x, acc[r]);
          acc[r] = fmaf(sv.y, w.y, acc[r]);
          acc[r] = fmaf(sv.z, w.z, acc[r]);
          acc[r] = fmaf(sv.w, w.w, acc[r]);
        }
      }
      __syncthreads();                  // all reads of s4 done
      // --- update + clip (finite inputs -> nan_to_num is a no-op) ---
#pragma unroll
      for (int r = 0; r < RR; ++r) {
        const float cc    = s_reg[r] - mean[r];
        const float drift = acc[r] + kCubic * cc * cc * cc + sig[r];
        float sn = fmaf(kDT, drift, s_reg[r]);
        sn = fminf(fmaxf(sn, -80.0f), 80.0f);
        s_reg[r] = sn;
        s_lin[r * kD + tid] = sn;
      }
    }
  }

  // --- write state + per-row sum of squares ---
  {
    float part[RR];
#pragma unroll
    for (int r = 0; r < RR; ++r) part[r] = s_reg[r] * s_reg[r];
#pragma unroll
    for (int o = 32; o > 0; o >>= 1) {
#pragma unroll
      for (int r = 0; r < RR; ++r) part[r] += __shfl_xor(part[r], o);
    }
    if (lane == 0) {
#pragma unroll
      for (int r = 0; r < RR; ++r) red[r][wid] = part[r];
    }
    __syncthreads();
#pragma unroll
    for (int r = 0; r < RR; ++r) {
      const int bb = b0 + r;
      if (bb < kB) {
        state[(size_t)bb * kD + tid] = s_reg[r];
        if (tid == 0) {
          float m = 0.0f;
#pragma unroll
          for (int w = 0; w < 8; ++w) m += red[r][w];
          ssq[bb] = m;
        }
      }
    }
  }
}

// ---------------------------------------------------------------------------
// K4: logits[b,v] = -sqrt(max(||s_b||^2 + ||a_v||^2 - 2 s_b.a_v, 0)) / temp
// Block covers 32 v-columns x all 256 b. K chunked by 32, tiles in LDS
// (stride 36 floats = 144B: 16B-aligned + bank-spread).
__global__ __launch_bounds__(256)
void k_logits(const float* __restrict__ state, const float* __restrict__ ssq,
              const float* __restrict__ sigs, const float* __restrict__ traw,
              float* __restrict__ out) {
  const int tid = threadIdx.x;
  const int v0  = blockIdx.x * VT;
  __shared__ float st[kB][36];    // 36 KB
  __shared__ float at[VT][36];    // 4.6 KB
  __shared__ float ssq_l[kB];

  ssq_l[tid] = ssq[tid];          // 256 threads == kB

  const int tv = tid & 31;        // this thread's v-column
  const int tb = tid >> 5;        // 0..7
  float acc[32];
#pragma unroll
  for (int i = 0; i < 32; ++i) acc[i] = 0.0f;
  float asq = 0.0f;               // ||a_v||^2, matches reference's explicit sum

  for (int kc = 0; kc < kD / 32; ++kc) {
    __syncthreads();              // previous compute done with tiles
    // load state chunk [256][32]: 8 float4 per thread, 128B-segment coalesced
#pragma unroll
    for (int i = 0; i < 8; ++i) {
      const int flat = tid + 256 * i;        // 0..2047
      const int b = flat >> 3, qq = flat & 7;
      const float4 v4 = *reinterpret_cast<const float4*>(
          state + ((size_t)b << 9) + (kc << 5) + (qq << 2));
      *reinterpret_cast<float4*>(&st[b][qq << 2]) = v4;
    }
    // load sigs chunk [32][32]
    {
      const int v = tid >> 3, qq = tid & 7;
      float4 a4 = {0.f, 0.f, 0.f, 0.f};
      if (v0 + v < kV)
        a4 = *reinterpret_cast<const float4*>(
            sigs + ((size_t)(v0 + v) << 9) + (kc << 5) + (qq << 2));
      *reinterpret_cast<float4*>(&at[v][qq << 2]) = a4;
    }
    __syncthreads();
#pragma unroll
    for (int kk = 0; kk < 8; ++kk) {
      const float4 a = *reinterpret_cast<const float4*>(&at[tv][kk << 2]);
      asq = fmaf(a.x, a.x, fmaf(a.y, a.y, fmaf(a.z, a.z, fmaf(a.w, a.w, asq))));
#pragma unroll
      for (int ib = 0; ib < 32; ++ib) {
        const float4 sv = *reinterpret_cast<const float4*>(&st[tb + 8 * ib][kk << 2]);
        acc[ib] = fmaf(sv.x, a.x, acc[ib]);
        acc[ib] = fmaf(sv.y, a.y, acc[ib]);
        acc[ib] = fmaf(sv.z, a.z, acc[ib]);
        acc[ib] = fmaf(sv.w, a.w, acc[ib]);
      }
    }
  }

  const float x  = traw[0];
  const float sp = log1pf(expf(x));               // softplus
  const float rt = 1.0f / fmaxf(sp, 1e-6f);
  const int v = v0 + tv;
  if (v < kV) {
#pragma unroll
    for (int ib = 0; ib < 32; ++ib) {
      const int b = tb + 8 * ib;
      const float sq = ssq_l[b] + asq - 2.0f * acc[ib];
      out[(size_t)b * kV + v] = -sqrtf(fmaxf(sq, 0.0f)) * rt;
    }
  }
}

// ---------------------------------------------------------------------------
extern "C" void kernel_launch(void* const* d_in, const int* in_sizes, int n_in,
                              void* d_out, int out_size, void* d_ws, size_t ws_size,
                              hipStream_t stream) {
  const int*   ids  = (const int*)d_in[0];     // [256,32]
  const float* emb  = (const float*)d_in[1];   // [50257,512]
  const float* dif  = (const float*)d_in[2];   // [512,512]
  const float* traw = (const float*)d_in[3];   // [1]
  float* out = (float*)d_out;                  // [256,50257]

  char* ws = (char*)d_ws;
  size_t off = 0;
  float*  all_sigs = (float*)(ws + off);  off += (size_t)kV * kD * sizeof(float);
  float4* w4       = (float4*)(ws + off); off += (size_t)kD * kD * sizeof(float);
  float*  state    = (float*)(ws + off);  off += (size_t)kB * kD * sizeof(float);
  float*  ssq      = (float*)(ws + off);  off += (size_t)kB * sizeof(float);

  hipLaunchKernelGGL(k_signals, dim3(kV), dim3(128), 0, stream, emb, all_sigs);
  hipLaunchKernelGGL(k_wprep, dim3((kD * kD / 4) / 256), dim3(256), 0, stream, dif, w4);
  hipLaunchKernelGGL(k_scan, dim3(SCAN_BLOCKS), dim3(512), 0, stream,
                     ids, all_sigs, w4, state, ssq);
  hipLaunchKernelGGL(k_logits, dim3((kV + VT - 1) / VT), dim3(256), 0, stream,
                     state, ssq, all_sigs, traw, out);
}

// Round 3
// 9304.242 us; speedup vs baseline: 1.1323x; 1.1323x over previous
//
#include <hip/hip_runtime.h>

// ---------------------------------------------------------------------------
// TorchAttractorLanguageModel. Round 2 findings: k_scan is per-CU L2-pull
// bound (1 MB f32 W streamed per block per step; measured 99 GB/s/CU = 41
// B/cy). Fix: f16 W (+f16 s broadcast) with v_dot2_f32_f16 and a depth-8
// double-buffered register prefetch pipeline that never drains across steps
// (W addresses are step-invariant, so the last phase prefetches chunk 0 of
// the NEXT step).
// ---------------------------------------------------------------------------

static constexpr int   kB     = 256;
static constexpr int   kT     = 32;
static constexpr int   kV     = 50257;
static constexpr int   kD     = 512;
static constexpr int   kSteps = 30;
static constexpr float kDT    = 0.04f;
static constexpr float kCubic = 0.008f;
static constexpr float kEpsLN = 1e-5f;

static constexpr int RR          = 3;                    // state rows per scan block
static constexpr int SCAN_BLOCKS = (kB + RR - 1) / RR;   // 86
static constexpr int VT          = 32;                   // v-columns per logits block

typedef _Float16 half1;
typedef _Float16 half2v __attribute__((ext_vector_type(2)));
union HU { unsigned int u; half2v h; half1 s[2]; };

#if defined(__has_builtin)
#if __has_builtin(__builtin_amdgcn_fdot2)
#define HAS_FDOT2 1
#endif
#endif

__device__ __forceinline__ float dot2acc(unsigned int a, unsigned int b, float c) {
  HU ua; ua.u = a;
  HU ub; ub.u = b;
#ifdef HAS_FDOT2
  return __builtin_amdgcn_fdot2(ua.h, ub.h, c, false);
#else
  c = fmaf((float)ua.s[0], (float)ub.s[0], c);
  return fmaf((float)ua.s[1], (float)ub.s[1], c);
#endif
}

// ---------------------------------------------------------------------------
// K1: all_sigs[v] = L2normalize(LayerNorm(emb[v]))  (no affine, biased var)
__global__ __launch_bounds__(128)
void k_signals(const float* __restrict__ emb, float* __restrict__ sigs) {
  const int row = blockIdx.x;
  const int tid = threadIdx.x;
  const float4 x = reinterpret_cast<const float4*>(emb + (size_t)row * kD)[tid];
  float s = x.x + x.y + x.z + x.w;
  float q = x.x * x.x + x.y * x.y + x.z * x.z + x.w * x.w;
#pragma unroll
  for (int o = 32; o > 0; o >>= 1) {
    s += __shfl_xor(s, o);
    q += __shfl_xor(q, o);
  }
  __shared__ float ls[2], lq[2];
  const int wid = tid >> 6;
  if ((tid & 63) == 0) { ls[wid] = s; lq[wid] = q; }
  __syncthreads();
  s = ls[0] + ls[1];
  q = lq[0] + lq[1];
  const float mu   = s * (1.0f / kD);
  const float var  = fmaxf(q * (1.0f / kD) - mu * mu, 0.0f);
  const float rstd = rsqrtf(var + kEpsLN);
  const float n     = rstd * sqrtf((float)kD * var);
  const float scale = rstd / fmaxf(n, 1e-12f);
  float4 y;
  y.x = (x.x - mu) * scale;
  y.y = (x.y - mu) * scale;
  y.z = (x.z - mu) * scale;
  y.w = (x.w - mu) * scale;
  reinterpret_cast<float4*>(sigs + (size_t)row * kD)[tid] = y;
}

// ---------------------------------------------------------------------------
// K2: pack diffusion to f16 pairs, layout w2[c][j][q] (dword = half2) with
// c=k-octet (0..63), j=output row (0..511), q=pair-in-octet (0..3):
//   w2 dword idx = ((c*512)+j)*4+q  holds (Dif[j][8c+2q], Dif[j][8c+2q+1]).
// Scan thread j then streams uint4 at uint4-index (c<<9)+j: 1 KB/wave, coalesced.
__global__ __launch_bounds__(256)
void k_wprep(const float* __restrict__ dif, unsigned int* __restrict__ w2) {
  const int idx = blockIdx.x * 256 + threadIdx.x;     // 131072 dwords
  const int q  = idx & 3;
  const int j  = (idx >> 2) & 511;
  const int c  = idx >> 11;
  const int k0 = c * 8 + q * 2;
  HU u;
  u.s[0] = (half1)dif[(size_t)j * kD + k0];
  u.s[1] = (half1)dif[(size_t)j * kD + k0 + 1];
  w2[idx] = u.u;
}

// ---------------------------------------------------------------------------
__device__ __forceinline__ void loadw(uint4 (&dst)[8], const uint4* __restrict__ wp,
                                      int c0) {
#pragma unroll
  for (int i = 0; i < 8; ++i) dst[i] = wp[(size_t)((c0 * 8 + i) << 9)];
}

__device__ __forceinline__ void compw(const uint4 (&w)[8],
                                      const unsigned short (*__restrict__ sh)[kD],
                                      int c0, float (&acc)[RR]) {
#pragma unroll
  for (int i = 0; i < 8; ++i) {
    const uint4 wv = w[i];
#pragma unroll
    for (int r = 0; r < RR; ++r) {
      const uint4 sv = *reinterpret_cast<const uint4*>(&sh[r][(c0 * 8 + i) * 8]);
      float a = acc[r];
      a = dot2acc(sv.x, wv.x, a);
      a = dot2acc(sv.y, wv.y, a);
      a = dot2acc(sv.z, wv.z, a);
      a = dot2acc(sv.w, wv.w, a);
      acc[r] = a;
    }
  }
}

// K3: the scan. One block owns RR rows for all 960 steps. W streamed from L2
// as f16 pairs with an 8-deep double-buffered prefetch; s broadcast from LDS
// as f16 pairs; f32 state/accumulate; mean via wave shuffle + LDS combine.
__global__ __launch_bounds__(512)
void k_scan(const int* __restrict__ ids, const float* __restrict__ sigs,
            const uint4* __restrict__ w2, float* __restrict__ state,
            float* __restrict__ ssq) {
  const int tid  = threadIdx.x;        // == output element j
  const int b0   = blockIdx.x * RR;
  const int wid  = tid >> 6;
  const int lane = tid & 63;

  __shared__ unsigned short s_h[RR][kD];   // f16 state broadcast (3 KB)
  __shared__ float red[RR][8];

  float s_reg[RR], sig[RR];
#pragma unroll
  for (int r = 0; r < RR; ++r) { s_reg[r] = 0.0f; s_h[r][tid] = 0; }

  const uint4* __restrict__ wp = w2 + tid;
  uint4 wA[8], wB[8];
  loadw(wA, wp, 0);                        // chunk 0 in flight before step 1

  for (int t = 0; t < kT; ++t) {
#pragma unroll
    for (int r = 0; r < RR; ++r) {
      int bb = b0 + r; if (bb >= kB) bb = 0;          // padded rows: harmless
      const int id = ids[bb * kT + t];
      sig[r] = sigs[(size_t)id * kD + tid];
    }
    for (int step = 0; step < kSteps; ++step) {
      // --- mean over D (register shuffle + LDS combine) ---
      float part[RR];
#pragma unroll
      for (int r = 0; r < RR; ++r) part[r] = s_reg[r];
#pragma unroll
      for (int o = 32; o > 0; o >>= 1) {
#pragma unroll
        for (int r = 0; r < RR; ++r) part[r] += __shfl_xor(part[r], o);
      }
      if (lane == 0) {
#pragma unroll
        for (int r = 0; r < RR; ++r) red[r][wid] = part[r];
      }
      __syncthreads();                  // B1: red + s_h(prev step) visible
      float mean[RR];
#pragma unroll
      for (int r = 0; r < RR; ++r) {
        float m = 0.0f;
#pragma unroll
        for (int w = 0; w < 8; ++w) m += red[r][w];
        mean[r] = m * (1.0f / kD);
      }
      // --- y = s @ Dif^T : 8 chunks, 2-window prefetch, never drained ---
      float acc[RR];
#pragma unroll
      for (int r = 0; r < RR; ++r) acc[r] = 0.0f;
#pragma unroll
      for (int np = 0; np < 4; ++np) {
        loadw(wB, wp, np * 2 + 1);               // next chunk in flight
        compw(wA, s_h, np * 2, acc);
        loadw(wA, wp, (np * 2 + 2) & 7);         // np=3 -> chunk 0 of NEXT step
        compw(wB, s_h, np * 2 + 1, acc);
      }
      __syncthreads();                  // B2: all s_h reads done
      // --- update + clip (finite inputs -> nan_to_num is a no-op) ---
#pragma unroll
      for (int r = 0; r < RR; ++r) {
        const float cc    = s_reg[r] - mean[r];
        const float drift = acc[r] + kCubic * cc * cc * cc + sig[r];
        float sn = fmaf(kDT, drift, s_reg[r]);
        sn = fminf(fmaxf(sn, -80.0f), 80.0f);
        s_reg[r] = sn;
        HU u; u.s[0] = (half1)sn;
        s_h[r][tid] = (unsigned short)(u.u & 0xffffu);
      }
    }
  }

  // --- write state + per-row sum of squares ---
  {
    float part[RR];
#pragma unroll
    for (int r = 0; r < RR; ++r) part[r] = s_reg[r] * s_reg[r];
#pragma unroll
    for (int o = 32; o > 0; o >>= 1) {
#pragma unroll
      for (int r = 0; r < RR; ++r) part[r] += __shfl_xor(part[r], o);
    }
    if (lane == 0) {
#pragma unroll
      for (int r = 0; r < RR; ++r) red[r][wid] = part[r];
    }
    __syncthreads();
#pragma unroll
    for (int r = 0; r < RR; ++r) {
      const int bb = b0 + r;
      if (bb < kB) {
        state[(size_t)bb * kD + tid] = s_reg[r];
        if (tid == 0) {
          float m = 0.0f;
#pragma unroll
          for (int w = 0; w < 8; ++w) m += red[r][w];
          ssq[bb] = m;
        }
      }
    }
  }
}

// ---------------------------------------------------------------------------
// K4: logits[b,v] = -sqrt(max(||s_b||^2 + ||a_v||^2 - 2 s_b.a_v, 0)) / temp
__global__ __launch_bounds__(256)
void k_logits(const float* __restrict__ state, const float* __restrict__ ssq,
              const float* __restrict__ sigs, const float* __restrict__ traw,
              float* __restrict__ out) {
  const int tid = threadIdx.x;
  const int v0  = blockIdx.x * VT;
  __shared__ float st[kB][36];    // 36 KB
  __shared__ float at[VT][36];    // 4.6 KB
  __shared__ float ssq_l[kB];

  ssq_l[tid] = ssq[tid];          // 256 threads == kB

  const int tv = tid & 31;        // this thread's v-column
  const int tb = tid >> 5;        // 0..7
  float acc[32];
#pragma unroll
  for (int i = 0; i < 32; ++i) acc[i] = 0.0f;
  float asq = 0.0f;               // ||a_v||^2, matches reference's explicit sum

  for (int kc = 0; kc < kD / 32; ++kc) {
    __syncthreads();              // previous compute done with tiles
#pragma unroll
    for (int i = 0; i < 8; ++i) {
      const int flat = tid + 256 * i;        // 0..2047
      const int b = flat >> 3, qq = flat & 7;
      const float4 v4 = *reinterpret_cast<const float4*>(
          state + ((size_t)b << 9) + (kc << 5) + (qq << 2));
      *reinterpret_cast<float4*>(&st[b][qq << 2]) = v4;
    }
    {
      const int v = tid >> 3, qq = tid & 7;
      float4 a4 = {0.f, 0.f, 0.f, 0.f};
      if (v0 + v < kV)
        a4 = *reinterpret_cast<const float4*>(
            sigs + ((size_t)(v0 + v) << 9) + (kc << 5) + (qq << 2));
      *reinterpret_cast<float4*>(&at[v][qq << 2]) = a4;
    }
    __syncthreads();
#pragma unroll
    for (int kk = 0; kk < 8; ++kk) {
      const float4 a = *reinterpret_cast<const float4*>(&at[tv][kk << 2]);
      asq = fmaf(a.x, a.x, fmaf(a.y, a.y, fmaf(a.z, a.z, fmaf(a.w, a.w, asq))));
#pragma unroll
      for (int ib = 0; ib < 32; ++ib) {
        const float4 sv = *reinterpret_cast<const float4*>(&st[tb + 8 * ib][kk << 2]);
        acc[ib] = fmaf(sv.x, a.x, acc[ib]);
        acc[ib] = fmaf(sv.y, a.y, acc[ib]);
        acc[ib] = fmaf(sv.z, a.z, acc[ib]);
        acc[ib] = fmaf(sv.w, a.w, acc[ib]);
      }
    }
  }

  const float x  = traw[0];
  const float sp = log1pf(expf(x));               // softplus
  const float rt = 1.0f / fmaxf(sp, 1e-6f);
  const int v = v0 + tv;
  if (v < kV) {
#pragma unroll
    for (int ib = 0; ib < 32; ++ib) {
      const int b = tb + 8 * ib;
      const float sq = ssq_l[b] + asq - 2.0f * acc[ib];
      out[(size_t)b * kV + v] = -sqrtf(fmaxf(sq, 0.0f)) * rt;
    }
  }
}

// ---------------------------------------------------------------------------
extern "C" void kernel_launch(void* const* d_in, const int* in_sizes, int n_in,
                              void* d_out, int out_size, void* d_ws, size_t ws_size,
                              hipStream_t stream) {
  const int*   ids  = (const int*)d_in[0];     // [256,32]
  const float* emb  = (const float*)d_in[1];   // [50257,512]
  const float* dif  = (const float*)d_in[2];   // [512,512]
  const float* traw = (const float*)d_in[3];   // [1]
  float* out = (float*)d_out;                  // [256,50257]

  char* ws = (char*)d_ws;
  size_t off = 0;
  float*        all_sigs = (float*)(ws + off);        off += (size_t)kV * kD * sizeof(float);
  unsigned int* w2       = (unsigned int*)(ws + off); off += (size_t)kD * kD / 2 * sizeof(unsigned int);
  float*        state    = (float*)(ws + off);        off += (size_t)kB * kD * sizeof(float);
  float*        ssq      = (float*)(ws + off);        off += (size_t)kB * sizeof(float);

  hipLaunchKernelGGL(k_signals, dim3(kV), dim3(128), 0, stream, emb, all_sigs);
  hipLaunchKernelGGL(k_wprep, dim3(kD * kD / 2 / 256), dim3(256), 0, stream, dif, w2);
  hipLaunchKernelGGL(k_scan, dim3(SCAN_BLOCKS), dim3(512), 0, stream,
                     ids, all_sigs, (const uint4*)w2, state, ssq);
  hipLaunchKernelGGL(k_logits, dim3((kV + VT - 1) / VT), dim3(256), 0, stream,
                     state, ssq, all_sigs, traw, out);
}